// Round 1
// baseline (360.808 us; speedup 1.0000x reference)
//
#include <hip/hip_runtime.h>
#include <math.h>

#define BB 16
#define AA 65536
#define GG 32

// workspace layout (bytes)
#define OFF_PACKED   0            // u64[BB*GG]                      4096
#define OFF_HIST     4096         // int[4][BB][256]                 65536
#define OFF_NUMPOS   69632       // int[BB]
#define OFF_LOCSUM   69696       // float[BB]
#define OFF_POSBCE   69760       // float[BB]
#define OFF_PREDCNT  69824       // int[BB]
#define OFF_NEGSUM   69888       // float[BB]
#define OFF_NGT      69952       // int[BB]
#define OFF_FORCE    131072      // u8[BB*AA]                        1 MiB
#define MEMSET_BYTES 2097152     // zero [0, 2MiB)
#define OFF_BESTIOU  2097152     // float[BB*AA]                     4 MiB
#define OFF_BESTIDX  6291456     // u8[BB*AA]                        1 MiB
#define OFF_NEGBCE   7340032     // float[BB*AA]                     4 MiB
// total ws used: 11534336 bytes

__device__ __forceinline__ float iou_exact(float ax, float ay, float az, float aw,
                                           float area_a,
                                           float gx, float gy, float gz, float gw,
                                           float area_g) {
    // bit-matches numpy: lt=max, rb=min, wh=clip(rb-lt,0), inter=w*h,
    // union=(area_a+area_g)-inter, iou=inter/(union+1e-6)
    float lx = fmaxf(ax, gx), ly = fmaxf(ay, gy);
    float rx = fminf(az, gz), ry = fminf(aw, gw);
    float w = fmaxf(__fsub_rn(rx, lx), 0.0f);
    float h = fmaxf(__fsub_rn(ry, ly), 0.0f);
    float inter = __fmul_rn(w, h);
    float uni = __fsub_rn(__fadd_rn(area_a, area_g), inter);
    return __fdiv_rn(inter, __fadd_rn(uni, 1e-6f));
}

__device__ __forceinline__ float sl1(float x, float y) {
    float d = fabsf(__fsub_rn(x, y));
    return (d < 1.0f) ? __fmul_rn(__fmul_rn(0.5f, d), d) : __fsub_rn(d, 0.5f);
}

// ---------------- K1: IoU, per-anchor best (max+first-argmax), per-gt argmax ----------------
__global__ __launch_bounds__(256) void k_iou(const float4* __restrict__ anchors,
                                             const float4* __restrict__ gt,
                                             float* __restrict__ best_iou,
                                             unsigned char* __restrict__ best_idx,
                                             unsigned long long* __restrict__ packed) {
    const int b = blockIdx.y;
    const int t = threadIdx.x;
    __shared__ float4 gts[GG];
    __shared__ float areag[GG];
    __shared__ unsigned long long red[4][GG];
    if (t < GG) {
        float4 g4 = gt[b * GG + t];
        gts[t] = g4;
        areag[t] = __fmul_rn(__fsub_rn(g4.z, g4.x), __fsub_rn(g4.w, g4.y));
    }
    __syncthreads();
    const int base = blockIdx.x * 1024;
    float4 an[4]; float aa[4]; float bi[4]; int bix[4]; int aidx[4];
#pragma unroll
    for (int j = 0; j < 4; ++j) {
        aidx[j] = base + j * 256 + t;
        an[j] = anchors[aidx[j]];
        aa[j] = __fmul_rn(__fsub_rn(an[j].z, an[j].x), __fsub_rn(an[j].w, an[j].y));
        bi[j] = -1.0f; bix[j] = 0;
    }
    const int lane = t & 63, wv = t >> 6;
    for (int g = 0; g < GG; ++g) {
        float4 gb = gts[g];
        float ag = areag[g];
        unsigned long long pk = 0ull;
#pragma unroll
        for (int j = 0; j < 4; ++j) {
            float iou = iou_exact(an[j].x, an[j].y, an[j].z, an[j].w, aa[j],
                                  gb.x, gb.y, gb.z, gb.w, ag);
            if (iou > bi[j]) { bi[j] = iou; bix[j] = g; }
            unsigned long long p = ((unsigned long long)__float_as_uint(iou) << 32)
                                 | (unsigned long long)(0xFFFFFFFFu - (unsigned)aidx[j]);
            if (p > pk) pk = p;
        }
#pragma unroll
        for (int off = 32; off; off >>= 1) {
            unsigned long long q = __shfl_xor(pk, off, 64);
            if (q > pk) pk = q;
        }
        if (lane == 0) red[wv][g] = pk;
    }
#pragma unroll
    for (int j = 0; j < 4; ++j) {
        best_iou[b * AA + aidx[j]] = bi[j];
        best_idx[b * AA + aidx[j]] = (unsigned char)bix[j];
    }
    __syncthreads();
    if (t < GG) {
        unsigned long long p = red[0][t];
#pragma unroll
        for (int w = 1; w < 4; ++w) if (red[w][t] > p) p = red[w][t];
        atomicMax(&packed[b * GG + t], p);
    }
}

// ---------------- K2: scatter best-anchor-per-gt into force_pos ----------------
__global__ void k_scatter(const unsigned long long* __restrict__ packed,
                          unsigned char* __restrict__ force_pos) {
    int i = blockIdx.x * 256 + threadIdx.x;
    if (i < BB * GG) {
        int b = i >> 5;
        unsigned int low = (unsigned int)(packed[i] & 0xFFFFFFFFull);
        unsigned int a = 0xFFFFFFFFu - low;
        force_pos[b * AA + a] = 1;
    }
}

// ---------------- K3: per-anchor pos/bce/loc + hist level 0 ----------------
__global__ __launch_bounds__(256) void k_anchor(const float4* __restrict__ bbox,
                                                const float* __restrict__ conf,
                                                const float4* __restrict__ gt,
                                                const float* __restrict__ best_iou,
                                                const unsigned char* __restrict__ best_idx,
                                                const unsigned char* __restrict__ force_pos,
                                                float* __restrict__ neg_bce,
                                                int* __restrict__ hist0,
                                                int* __restrict__ num_pos,
                                                float* __restrict__ loc_sum,
                                                float* __restrict__ posbce,
                                                int* __restrict__ pred_cnt) {
    const int b = blockIdx.y, t = threadIdx.x;
    const int a = blockIdx.x * 256 + t;
    __shared__ float4 gts[GG];
    __shared__ int sh[256];
    __shared__ float sloc[4], spb[4];
    __shared__ int snp[4], spc[4];
    sh[t] = 0;
    if (t < GG) gts[t] = gt[b * GG + t];
    __syncthreads();
    const int idx = b * AA + a;
    float p = conf[idx];
    bool pos = (best_iou[idx] > 0.5f) || (force_pos[idx] != 0);
    float bce, nb;
    if (pos) { bce = -fmaxf(logf(p), -100.0f); nb = 0.0f; }
    else     { bce = -fmaxf(log1pf(-p), -100.0f); nb = bce; }
    neg_bce[idx] = nb;
    if (!pos) atomicAdd(&sh[__float_as_uint(nb) >> 24], 1);
    float loc = 0.0f;
    if (pos) {
        float4 bp = bbox[idx];
        float4 gb = gts[best_idx[idx]];
        float pcx = __fmul_rn(__fadd_rn(bp.x, bp.z), 0.5f);
        float pcy = __fmul_rn(__fadd_rn(bp.y, bp.w), 0.5f);
        float pw = __fsub_rn(bp.z, bp.x), ph = __fsub_rn(bp.w, bp.y);
        float gcx = __fmul_rn(__fadd_rn(gb.x, gb.z), 0.5f);
        float gcy = __fmul_rn(__fadd_rn(gb.y, gb.w), 0.5f);
        float gw = __fsub_rn(gb.z, gb.x), gh = __fsub_rn(gb.w, gb.y);
        loc = __fadd_rn(__fadd_rn(__fadd_rn(sl1(pcx, gcx), sl1(pcy, gcy)), sl1(pw, gw)), sl1(ph, gh));
    }
    int np_ = pos ? 1 : 0;
    int pc = (p > 0.5f) ? 1 : 0;
    float pb = pos ? bce : 0.0f;
#pragma unroll
    for (int off = 32; off; off >>= 1) {
        loc += __shfl_xor(loc, off, 64);
        pb  += __shfl_xor(pb, off, 64);
        np_ += __shfl_xor(np_, off, 64);
        pc  += __shfl_xor(pc, off, 64);
    }
    const int lane = t & 63, wv = t >> 6;
    if (lane == 0) { sloc[wv] = loc; spb[wv] = pb; snp[wv] = np_; spc[wv] = pc; }
    __syncthreads();
    if (t == 0) {
        float L = sloc[0] + sloc[1] + sloc[2] + sloc[3];
        float P = spb[0] + spb[1] + spb[2] + spb[3];
        int   N = snp[0] + snp[1] + snp[2] + snp[3];
        int   C = spc[0] + spc[1] + spc[2] + spc[3];
        if (L != 0.0f) atomicAdd(&loc_sum[b], L);
        if (P != 0.0f) atomicAdd(&posbce[b], P);
        if (N) atomicAdd(&num_pos[b], N);
        if (C) atomicAdd(&pred_cnt[b], C);
    }
    if (sh[t]) atomicAdd(&hist0[b * 256 + t], sh[t]);
}

// ---------------- radix-select scan of one 8-bit level (256 threads) ----------------
__device__ __forceinline__ void scan_level(const int* __restrict__ histL, int t,
                                           int* ss, int* sres,
                                           unsigned int* prefix, int* k, int shift) {
    int kk = *k;
    ss[t] = histL[t];
    __syncthreads();
#pragma unroll
    for (int off = 1; off < 256; off <<= 1) {
        int v = (t + off < 256) ? ss[t + off] : 0;
        __syncthreads();
        ss[t] += v;
        __syncthreads();
    }
    // inclusive suffix sums: ss[t] = count(digit >= t). Find d: ss[d]>=k, ss[d+1]<k
    if (ss[t] >= kk && (t == 255 || ss[t + 1] < kk)) {
        sres[0] = t;
        sres[1] = (t == 255) ? kk : (kk - ss[t + 1]);
    }
    __syncthreads();
    *prefix |= ((unsigned int)sres[0]) << shift;
    *k = sres[1];
    __syncthreads();
}

// ---------------- K4: radix histogram passes 1..3 ----------------
__global__ __launch_bounds__(256) void k_hist(const float* __restrict__ neg_bce,
                                              int* __restrict__ hist,
                                              const int* __restrict__ num_pos,
                                              int pass) {
    const int b = blockIdx.y, t = threadIdx.x;
    __shared__ int ss[256];
    __shared__ int sres[2];
    __shared__ int sh[256];
    int np_ = num_pos[b];
    int k = min(3 * np_, AA - np_);
    if (k <= 0) return;
    unsigned int prefix = 0;
    for (int L = 0; L < pass; ++L)
        scan_level(&hist[(L * BB + b) * 256], t, ss, sres, &prefix, &k, 24 - 8 * L);
    sh[t] = 0;
    __syncthreads();
    const unsigned int pmask = 0xFFFFFFFFu << (32 - 8 * pass);
    const int shift = 24 - 8 * pass;
    for (int a = blockIdx.x * 256 + t; a < AA; a += gridDim.x * 256) {
        unsigned int bits = __float_as_uint(neg_bce[b * AA + a]);
        if ((bits & pmask) == prefix) atomicAdd(&sh[(bits >> shift) & 0xFFu], 1);
    }
    __syncthreads();
    if (sh[t]) atomicAdd(&hist[(pass * BB + b) * 256 + t], sh[t]);
}

// ---------------- K5: sum of values strictly greater than kth value ----------------
__global__ __launch_bounds__(256) void k_topk(const float* __restrict__ neg_bce,
                                              const int* __restrict__ hist,
                                              const int* __restrict__ num_pos,
                                              float* __restrict__ negsum,
                                              int* __restrict__ ngt) {
    const int b = blockIdx.y, t = threadIdx.x;
    __shared__ int ss[256];
    __shared__ int sres[2];
    __shared__ float sfs[4];
    __shared__ int sfc[4];
    int np_ = num_pos[b];
    int k = min(3 * np_, AA - np_);
    if (k <= 0) return;
    unsigned int prefix = 0;
    for (int L = 0; L < 4; ++L)
        scan_level(&hist[(L * BB + b) * 256], t, ss, sres, &prefix, &k, 24 - 8 * L);
    const float vk = __uint_as_float(prefix);
    float s = 0.0f; int c = 0;
    for (int a = blockIdx.x * 256 + t; a < AA; a += gridDim.x * 256) {
        float v = neg_bce[b * AA + a];
        if (v > vk) { s += v; c++; }
    }
#pragma unroll
    for (int off = 32; off; off >>= 1) { s += __shfl_xor(s, off, 64); c += __shfl_xor(c, off, 64); }
    const int lane = t & 63, wv = t >> 6;
    if (lane == 0) { sfs[wv] = s; sfc[wv] = c; }
    __syncthreads();
    if (t == 0) {
        float S = sfs[0] + sfs[1] + sfs[2] + sfs[3];
        int   C = sfc[0] + sfc[1] + sfc[2] + sfc[3];
        if (S != 0.0f) atomicAdd(&negsum[b], S);
        if (C) atomicAdd(&ngt[b], C);
    }
}

// ---------------- K6: final combine ----------------
__global__ __launch_bounds__(256) void k_final(const float* __restrict__ best_iou_last,
                                               const int* __restrict__ hist,
                                               const int* __restrict__ num_pos,
                                               const float* __restrict__ loc_sum,
                                               const float* __restrict__ posbce,
                                               const float* __restrict__ negsum,
                                               const int* __restrict__ ngt,
                                               const int* __restrict__ pred_cnt,
                                               float* __restrict__ out) {
    const int t = threadIdx.x;
    __shared__ int ss[256];
    __shared__ int sres[2];
    __shared__ float sconf;
    __shared__ float sfs[4];
    __shared__ int sfc[4];
    if (t == 0) sconf = 0.0f;
    __syncthreads();
    for (int b = 0; b < BB; ++b) {
        int np_ = num_pos[b];
        int k0 = min(3 * np_, AA - np_);
        float add = posbce[b] + negsum[b];
        if (k0 > 0) {
            unsigned int prefix = 0; int k = k0;
            for (int L = 0; L < 4; ++L)
                scan_level(&hist[(L * BB + b) * 256], t, ss, sres, &prefix, &k, 24 - 8 * L);
            float vk = __uint_as_float(prefix);
            add += (float)(k0 - ngt[b]) * vk;
        }
        if (t == 0) sconf += add;
        __syncthreads();
    }
    // mean_iou over last image
    float s = 0.0f; int c = 0;
    for (int a = t; a < AA; a += 256) {
        float v = best_iou_last[a];
        if (v > 0.0f) { s += v; c++; }
    }
#pragma unroll
    for (int off = 32; off; off >>= 1) { s += __shfl_xor(s, off, 64); c += __shfl_xor(c, off, 64); }
    const int lane = t & 63, wv = t >> 6;
    if (lane == 0) { sfs[wv] = s; sfc[wv] = c; }
    __syncthreads();
    if (t == 0) {
        float S = sfs[0] + sfs[1] + sfs[2] + sfs[3];
        int   C = sfc[0] + sfc[1] + sfc[2] + sfc[3];
        int npos_t = 0; float loc_t = 0.0f, cnt_t = 0.0f;
        for (int b = 0; b < BB; ++b) {
            npos_t += num_pos[b];
            loc_t += loc_sum[b];
            float diff = fabsf((float)(pred_cnt[b] - GG));
            cnt_t += (diff <= 3.0f) ? diff * 0.2f
                                    : 0.6f + 0.2f * logf(fmaxf(diff - 2.0f, 1.0f));
        }
        float total_count = cnt_t / (float)BB;
        float npos = (float)max(1, npos_t);
        float total_loc = loc_t / npos;
        float total_conf = sconf / npos;
        float mean_iou = (C > 0) ? (S / (float)max(C, 1)) : 0.1f;
        float q = fminf(fmaxf(1.0f - mean_iou, 0.1f), 0.9f);
        float dyn = 1.0f + q;
        out[0] = dyn * total_loc + total_conf + 0.2f * total_count;
        out[1] = total_conf;
        out[2] = total_loc;
        out[3] = total_count;
        out[4] = mean_iou;
    }
}

extern "C" void kernel_launch(void* const* d_in, const int* in_sizes, int n_in,
                              void* d_out, int out_size, void* d_ws, size_t ws_size,
                              hipStream_t stream) {
    (void)in_sizes; (void)n_in; (void)out_size; (void)ws_size;
    const float* bbox    = (const float*)d_in[0];  // [B,A,4]
    const float* conf    = (const float*)d_in[1];  // [B,A]
    const float* anchors = (const float*)d_in[2];  // [A,4]
    const float* gt      = (const float*)d_in[3];  // [B,G,4]
    char* ws = (char*)d_ws;
    unsigned long long* packed = (unsigned long long*)(ws + OFF_PACKED);
    int*   hist     = (int*)(ws + OFF_HIST);
    int*   num_pos  = (int*)(ws + OFF_NUMPOS);
    float* loc_sum  = (float*)(ws + OFF_LOCSUM);
    float* posbce   = (float*)(ws + OFF_POSBCE);
    int*   pred_cnt = (int*)(ws + OFF_PREDCNT);
    float* negsum   = (float*)(ws + OFF_NEGSUM);
    int*   ngt      = (int*)(ws + OFF_NGT);
    unsigned char* force_pos = (unsigned char*)(ws + OFF_FORCE);
    float* best_iou = (float*)(ws + OFF_BESTIOU);
    unsigned char* best_idx = (unsigned char*)(ws + OFF_BESTIDX);
    float* neg_bce  = (float*)(ws + OFF_NEGBCE);

    hipMemsetAsync(d_ws, 0, MEMSET_BYTES, stream);
    k_iou<<<dim3(64, BB), 256, 0, stream>>>((const float4*)anchors, (const float4*)gt,
                                            best_iou, best_idx, packed);
    k_scatter<<<2, 256, 0, stream>>>(packed, force_pos);
    k_anchor<<<dim3(256, BB), 256, 0, stream>>>((const float4*)bbox, conf, (const float4*)gt,
                                                best_iou, best_idx, force_pos, neg_bce,
                                                hist, num_pos, loc_sum, posbce, pred_cnt);
    for (int pass = 1; pass <= 3; ++pass)
        k_hist<<<dim3(64, BB), 256, 0, stream>>>(neg_bce, hist, num_pos, pass);
    k_topk<<<dim3(64, BB), 256, 0, stream>>>(neg_bce, hist, num_pos, negsum, ngt);
    k_final<<<1, 256, 0, stream>>>(best_iou + (size_t)(BB - 1) * AA, hist, num_pos,
                                   loc_sum, posbce, negsum, ngt, pred_cnt, (float*)d_out);
}